// Round 4
// baseline (15520.154 us; speedup 1.0000x reference)
//
#include <hip/hip_runtime.h>
#include <hip/hip_bf16.h>
#include <math.h>

#define T_STEPS 4096
#define IN_DIM  512
#define HID     2048
#define LEAK    0.3f

// ---------------------------------------------------------------------------
// Phase 1: P = U @ Win^T + bias, written directly into d_out (T x HID, f32)
// ---------------------------------------------------------------------------
#define GBM 64
#define GBN 64
#define GBK 32

__global__ __launch_bounds__(256) void gemm_p(const float* __restrict__ U,
                                              const float* __restrict__ Win,
                                              const float* __restrict__ bias,
                                              float* __restrict__ P) {
  __shared__ float As[GBM][GBK + 1];
  __shared__ float Bs[GBN][GBK + 1];
  const int bm = blockIdx.x, bn = blockIdx.y;
  const int tid = threadIdx.x;
  const int tx = tid & 15, ty = tid >> 4;

  float acc[4][4];
#pragma unroll
  for (int m = 0; m < 4; ++m)
#pragma unroll
    for (int n = 0; n < 4; ++n) acc[m][n] = 0.f;

  const float* Ub = U + (size_t)bm * GBM * IN_DIM;
  const float* Wb = Win + (size_t)bn * GBN * IN_DIM;

  for (int k0 = 0; k0 < IN_DIM; k0 += GBK) {
#pragma unroll
    for (int v = 0; v < 2; ++v) {
      const int f4 = v * 256 + tid;
      const int row = f4 >> 3;
      const int c4 = (f4 & 7) << 2;
      const float4 a = *(const float4*)(Ub + (size_t)row * IN_DIM + k0 + c4);
      As[row][c4 + 0] = a.x; As[row][c4 + 1] = a.y;
      As[row][c4 + 2] = a.z; As[row][c4 + 3] = a.w;
      const float4 b = *(const float4*)(Wb + (size_t)row * IN_DIM + k0 + c4);
      Bs[row][c4 + 0] = b.x; Bs[row][c4 + 1] = b.y;
      Bs[row][c4 + 2] = b.z; Bs[row][c4 + 3] = b.w;
    }
    __syncthreads();
#pragma unroll 8
    for (int k = 0; k < GBK; ++k) {
      float a[4], b[4];
#pragma unroll
      for (int m = 0; m < 4; ++m) a[m] = As[ty * 4 + m][k];
#pragma unroll
      for (int n = 0; n < 4; ++n) b[n] = Bs[tx * 4 + n][k];
#pragma unroll
      for (int m = 0; m < 4; ++m)
#pragma unroll
        for (int n = 0; n < 4; ++n)
          acc[m][n] = fmaf(a[m], b[n], acc[m][n]);
    }
    __syncthreads();
  }

#pragma unroll
  for (int m = 0; m < 4; ++m) {
    const int gr = bm * GBM + ty * 4 + m;
#pragma unroll
    for (int n = 0; n < 4; ++n) {
      const int gc = bn * GBN + tx * 4 + n;
      P[(size_t)gr * HID + gc] = acc[m][n] + bias[gc];
    }
  }
}

// ---------------------------------------------------------------------------
// Phase 2: persistent recurrence, single-hop tagged-word exchange.
//   - h published as 64-bit {tag = t+1, f32 bits} via relaxed AGENT-scope
//     atomic store (bypasses non-coherent XCD L2, visible at LLC).
//   - CONCURRENT poll: all 4 tagged words loaded back-to-back per round
//     (1 LLC RTT/round instead of 4 serial RTTs); ready-transition is
//     monotonic so the final round's values are valid.
//   - W fragment FORCED into registers via asm barrier (compiler otherwise
//     sinks the loads into the t-loop and re-streams W from L2 every step
//     -- round 1-3 showed VGPR_Count 80-84, impossible with W resident).
//   - fetch -> LDS -> compute; own row's h tracked in a register.
// ---------------------------------------------------------------------------
#define NB   64                  // blocks
#define NT   512                 // threads per block
#define RPB  (HID / NB)          // 32 rows per block
#define TPR  (NT / RPB)          // 16 threads per row
#define NF4  (HID / (TPR * 4))   // 32 float4 chunks per thread

__device__ __forceinline__ float fast_tanh(float x) {
  const float e = __expf(2.f * x);
  return 1.f - 2.f / (e + 1.f);
}

__device__ __forceinline__ void pub(unsigned long long* p, unsigned tag, float v) {
  const unsigned long long w =
      ((unsigned long long)tag << 32) | (unsigned long long)__float_as_uint(v);
  __hip_atomic_store(p, w, __ATOMIC_RELAXED, __HIP_MEMORY_SCOPE_AGENT);
}

__global__ __launch_bounds__(NT, 1) void esn_recur(const float* __restrict__ W,
                                                   float* __restrict__ out,
                                                   unsigned long long* __restrict__ slots) {
  const int tid = threadIdx.x;
  const int j   = tid & (TPR - 1);       // lane within row
  const int rl  = tid >> 4;              // local row
  const int row = blockIdx.x * RPB + rl;

  __shared__ float hs[HID];              // 8 KB staging for h_{t-1}

  // Load W fragment and FORCE it to stay in VGPRs across the whole t-loop.
  float4 wreg[NF4];
  const float4* wrow = (const float4*)(W + (size_t)row * HID);
#pragma unroll
  for (int i = 0; i < NF4; ++i) wreg[i] = wrow[i * TPR + j];
#pragma unroll
  for (int i = 0; i < NF4; ++i) {
    asm volatile("" : "+v"(wreg[i].x), "+v"(wreg[i].y),
                      "+v"(wreg[i].z), "+v"(wreg[i].w));
  }

  // ---- t = 0: h0 = leak * tanh(P0), publish with tag 1 into slot 0 ----
  float hp = LEAK * fast_tanh(out[row]); // all 16 lanes compute identically
  if (j == 0) {
    pub(&slots[row], 1u, hp);
    out[row] = hp;
  }

  for (int t = 1; t < T_STEPS; ++t) {
    float* __restrict__ ocur = out + (size_t)t * HID;
    const float p = ocur[row];           // issue early; hides under the spin

    // ---- fetch: poll 4 tagged words CONCURRENTLY (1 RTT per round) ----
    const unsigned long long* __restrict__ s4 =
        slots + (size_t)((t - 1) & 1) * HID + (size_t)tid * 4;
    const unsigned long long we = (unsigned long long)(unsigned)t << 32;
    unsigned long long w0, w1, w2, w3;
    do {
      w0 = __hip_atomic_load(&s4[0], __ATOMIC_RELAXED, __HIP_MEMORY_SCOPE_AGENT);
      w1 = __hip_atomic_load(&s4[1], __ATOMIC_RELAXED, __HIP_MEMORY_SCOPE_AGENT);
      w2 = __hip_atomic_load(&s4[2], __ATOMIC_RELAXED, __HIP_MEMORY_SCOPE_AGENT);
      w3 = __hip_atomic_load(&s4[3], __ATOMIC_RELAXED, __HIP_MEMORY_SCOPE_AGENT);
    } while ((((w0 ^ we) | (w1 ^ we) | (w2 ^ we) | (w3 ^ we)) >> 32) != 0ull);

    float4 hv4;
    hv4.x = __uint_as_float((unsigned)w0);
    hv4.y = __uint_as_float((unsigned)w1);
    hv4.z = __uint_as_float((unsigned)w2);
    hv4.w = __uint_as_float((unsigned)w3);

    __syncthreads();                     // prior step's LDS reads are done
    *(float4*)&hs[tid * 4] = hv4;
    __syncthreads();                     // h_{t-1} staged

    // ---- compute phase ----
    float4 acc = make_float4(0.f, 0.f, 0.f, 0.f);
#pragma unroll
    for (int i = 0; i < NF4; ++i) {
      const float4 hv = *(const float4*)&hs[(i * TPR + j) * 4];
      acc.x = fmaf(wreg[i].x, hv.x, acc.x);
      acc.y = fmaf(wreg[i].y, hv.y, acc.y);
      acc.z = fmaf(wreg[i].z, hv.z, acc.z);
      acc.w = fmaf(wreg[i].w, hv.w, acc.w);
    }
    float a = (acc.x + acc.y) + (acc.z + acc.w);
    a += __shfl_xor(a, 1, TPR);
    a += __shfl_xor(a, 2, TPR);
    a += __shfl_xor(a, 4, TPR);
    a += __shfl_xor(a, 8, TPR);          // all lanes hold the full dot

    const float h = (1.f - LEAK) * hp + LEAK * fast_tanh(p + a);
    hp = h;
    if (j == 0) {
      pub(&slots[(size_t)(t & 1) * HID + row], (unsigned)(t + 1), h);
      ocur[row] = h;                     // plain cached store (own XCD only)
    }
  }
}

// ---------------------------------------------------------------------------
extern "C" void kernel_launch(void* const* d_in, const int* in_sizes, int n_in,
                              void* d_out, int out_size, void* d_ws, size_t ws_size,
                              hipStream_t stream) {
  const float* U    = (const float*)d_in[0];
  const float* Win  = (const float*)d_in[1];
  const float* W    = (const float*)d_in[2];
  const float* bias = (const float*)d_in[3];
  float* out = (float*)d_out;
  unsigned long long* slots = (unsigned long long*)d_ws;

  // wipe tags (also clears stale tags between graph replays); tag 0 is
  // never a valid tag (tags are t+1 >= 1), so memset can't false-match
  hipMemsetAsync(d_ws, 0, 2 * HID * sizeof(unsigned long long), stream);

  dim3 ggrid(T_STEPS / GBM, HID / GBN);
  gemm_p<<<ggrid, 256, 0, stream>>>(U, Win, bias, out);

  esn_recur<<<NB, NT, 0, stream>>>(W, out, slots);
}